// Round 2
// baseline (4088.614 us; speedup 1.0000x reference)
//
#include <hip/hip_runtime.h>
#include <stdint.h>

// Bidirectional GRU, 6 layers, H=256, S=512, B=10, fp32 in/out (bf16 MFMA inside).
// Only 7 scans matter: fwd layers 0..5 + bwd layer 5 (reference slices
// layer_input[..., :128] == first half of fwd output, so bwd0..4 are dead).
// Scan s uses 4 workgroups (64 hidden units each), W fragments in VGPRs
// (converted fp32->bf16 once), per-step h all-to-all via agent-scope flags.

typedef short short8 __attribute__((ext_vector_type(8)));
typedef float floatx4 __attribute__((ext_vector_type(4)));

#define HIDDEN 256
#define SEQ 512
#define BATCH 10
#define BPAD 16

// ws layout (ushort elems): xhist[5][512][16][128] | hring[7][4][16][256] | flags
#define XHIST_SCAN (SEQ * BPAD * 128)            // 1,048,576
#define XHIST_TOTAL (5 * XHIST_SCAN)             // 5,242,880
#define HRING_SCAN (4 * BPAD * HIDDEN)           // 16,384
#define HRING_TOTAL (7 * HRING_SCAN)             // 114,688
#define FLAG_OFF_BYTES ((size_t)(XHIST_TOTAL + HRING_TOTAL) * 2)  // ~10.7 MB

__device__ __forceinline__ unsigned short f2bf(float f) {
    union { float f; unsigned int i; } v; v.f = f;
    unsigned int u = v.i;
    u += 0x7fffu + ((u >> 16) & 1u);   // round-to-nearest-even
    return (unsigned short)(u >> 16);
}
__device__ __forceinline__ short8 ld8f(const float* p) {  // 8 fp32 -> bf16x8 frag
    float4 a = *(const float4*)p;
    float4 b = *(const float4*)(p + 4);
    short8 r;
    r[0] = (short)f2bf(a.x); r[1] = (short)f2bf(a.y);
    r[2] = (short)f2bf(a.z); r[3] = (short)f2bf(a.w);
    r[4] = (short)f2bf(b.x); r[5] = (short)f2bf(b.y);
    r[6] = (short)f2bf(b.z); r[7] = (short)f2bf(b.w);
    return r;
}
__device__ __forceinline__ float sigmoidf_(float x) { return 1.0f / (1.0f + __expf(-x)); }
__device__ __forceinline__ float tanhf_(float x) {
    float e = __expf(2.0f * x);
    return 1.0f - 2.0f / (e + 1.0f);
}

__global__ __launch_bounds__(256, 1)
void gru_pipeline(const float* __restrict__ x,
                  const float* __restrict__ wihl0,
                  const float* __restrict__ wihrest,
                  const float* __restrict__ whh,
                  float* __restrict__ out,
                  unsigned short* __restrict__ xhist,
                  unsigned short* __restrict__ hring,
                  int* __restrict__ flags)
{
    const int scan  = blockIdx.x & 7;   // XCD-affinity heuristic only
    const int chunk = blockIdx.x >> 3;  // 0..3, owns hidden units [64*chunk, 64*chunk+64)
    if (scan >= 7) return;

    const bool isBwd = (scan == 6);
    const int layer = isBwd ? 5 : scan;
    const int dir = isBwd ? 1 : 0;

    const float* wih; int wih_stride;
    if (layer == 0) { wih = wihl0 + (size_t)dir * 768 * 128; wih_stride = 128; }
    else { wih = wihrest + ((size_t)((layer - 1) * 2 + dir)) * 768 * 512; wih_stride = 512; }
    const float* whhp = whh + ((size_t)(layer * 2 + dir)) * 768 * HIDDEN;

    const int prod = (layer == 0) ? -1 : (layer - 1);
    const unsigned short* xh = (prod >= 0) ? (xhist + (size_t)prod * XHIST_SCAN) : nullptr;
    unsigned short* myring = hring + (size_t)scan * HRING_SCAN;

    const int tid  = threadIdx.x;
    const int wave = tid >> 6;
    const int lane = tid & 63;
    const int n16  = lane & 15;   // gate column within tile / batch row for A frags
    const int quad = lane >> 4;
    const int j = chunk * 64 + wave * 16 + n16;   // this lane's hidden unit

    // ---- W fragments (MFMA B operand), bf16, VGPR-resident for the whole scan ----
    // B[k][n]: n = lane&15 -> gate row (g*256 + j); k = q*32 + quad*8 + i
    short8 bx[3][4];
    short8 bh[3][8];
#pragma unroll
    for (int g = 0; g < 3; ++g) {
        const int row = g * HIDDEN + j;
        const float* wr = wih + (size_t)row * wih_stride;
#pragma unroll
        for (int q = 0; q < 4; ++q) bx[g][q] = ld8f(wr + q * 32 + quad * 8);
        const float* hr = whhp + (size_t)row * HIDDEN;
#pragma unroll
        for (int q = 0; q < 8; ++q) bh[g][q] = ld8f(hr + q * 32 + quad * 8);
    }

    // Flags: monotonic completed-step counters, one per (scan, chunk)
    int* myflag    = flags + scan * 4 + chunk;
    int* scanflags = flags + scan * 4;
    int peer[3];
    { int c = 0; for (int k2 = 0; k2 < 4; ++k2) if (k2 != chunk) peer[c++] = k2; }
    int* pflag = (prod >= 0) ? (flags + prod * 4) : nullptr;

    float hprev[4] = {0.f, 0.f, 0.f, 0.f};
    int xSeen = 0;
    const int bmA = (n16 > 9) ? 9 : n16;  // clamp batch row for layer-0 x loads

    for (int t = 0; t < SEQ; ++t) {
        const int tx = isBwd ? (SEQ - 1 - t) : t;

        // --- wait for x(t) from producer (its chunks 0,1 cover j<128) ---
        if (pflag) {
            const int need = isBwd ? SEQ : (t + 1);  // bwd5 needs ALL of fwd4
            if (xSeen < need) {
                while (true) {
                    int v0 = __hip_atomic_load(&pflag[0], __ATOMIC_RELAXED, __HIP_MEMORY_SCOPE_AGENT);
                    int v1 = __hip_atomic_load(&pflag[1], __ATOMIC_RELAXED, __HIP_MEMORY_SCOPE_AGENT);
                    int m = v0 < v1 ? v0 : v1;
                    if (m >= need) { xSeen = m; break; }
                    __builtin_amdgcn_s_sleep(1);
                }
                __builtin_amdgcn_fence(__ATOMIC_ACQUIRE, "agent");
            }
        }

        // --- A_x fragments: A[m=batch=lane&15][k=q*32+quad*8+i] ---
        short8 ax[4];
        if (layer == 0) {
            const float* xrow = x + (size_t)tx * (BATCH * 128) + (size_t)bmA * 128;
#pragma unroll
            for (int q = 0; q < 4; ++q) ax[q] = ld8f(xrow + q * 32 + quad * 8);
        } else {
            const unsigned short* xrow = xh + (size_t)tx * (BPAD * 128) + (size_t)n16 * 128;
#pragma unroll
            for (int q = 0; q < 4; ++q) ax[q] = *(const short8*)(xrow + q * 32 + quad * 8);
        }

        floatx4 cx[3], ch[3];
#pragma unroll
        for (int g = 0; g < 3; ++g) {
            cx[g] = (floatx4){0.f, 0.f, 0.f, 0.f};
            ch[g] = (floatx4){0.f, 0.f, 0.f, 0.f};
        }

#pragma unroll
        for (int g = 0; g < 3; ++g)
#pragma unroll
            for (int q = 0; q < 4; ++q)
                cx[g] = __builtin_amdgcn_mfma_f32_16x16x32_bf16(ax[q], bx[g][q], cx[g], 0, 0, 0);

        // --- h-part: wait for all 4 chunks' h(t-1), then MFMA over K=256 ---
        if (t > 0) {
            while (true) {
                int v0 = __hip_atomic_load(&scanflags[peer[0]], __ATOMIC_RELAXED, __HIP_MEMORY_SCOPE_AGENT);
                int v1 = __hip_atomic_load(&scanflags[peer[1]], __ATOMIC_RELAXED, __HIP_MEMORY_SCOPE_AGENT);
                int v2 = __hip_atomic_load(&scanflags[peer[2]], __ATOMIC_RELAXED, __HIP_MEMORY_SCOPE_AGENT);
                int m = v0 < v1 ? v0 : v1; m = m < v2 ? m : v2;
                if (m >= t) break;
                __builtin_amdgcn_s_sleep(1);
            }
            __builtin_amdgcn_fence(__ATOMIC_ACQUIRE, "agent");

            const unsigned short* hrow = myring + (size_t)((t - 1) & 3) * (BPAD * HIDDEN)
                                       + (size_t)n16 * HIDDEN;
            short8 ah[8];
#pragma unroll
            for (int q = 0; q < 8; ++q) ah[q] = *(const short8*)(hrow + q * 32 + quad * 8);
#pragma unroll
            for (int g = 0; g < 3; ++g)
#pragma unroll
                for (int q = 0; q < 8; ++q)
                    ch[g] = __builtin_amdgcn_mfma_f32_16x16x32_bf16(ah[q], bh[g][q], ch[g], 0, 0, 0);
        }

        // --- nonlinearity + h update + stores ---
        // C/D layout: col = lane&15 = hidden unit j, row = quad*4 + reg = batch
        unsigned short* rst = myring + (size_t)(t & 3) * (BPAD * HIDDEN) + j;
        unsigned short* xst = (scan < 5 && j < 128)
            ? (xhist + (size_t)scan * XHIST_SCAN + (size_t)t * (BPAD * 128) + j) : nullptr;
#pragma unroll
        for (int r = 0; r < 4; ++r) {
            const int b = quad * 4 + r;
            float rr = sigmoidf_(cx[0][r] + ch[0][r]);
            float zz = sigmoidf_(cx[1][r] + ch[1][r]);
            float nn = tanhf_(cx[2][r] + rr * ch[2][r]);
            float hn = (1.0f - zz) * nn + zz * hprev[r];
            hprev[r] = hn;
            unsigned short hb = f2bf(hn);
            rst[(size_t)b * HIDDEN] = hb;
            if (xst) xst[(size_t)b * 128] = hb;
            if (scan >= 5 && b < BATCH) {
                // fwd5 -> out cols [0,256); bwd5 in scan order (NOT re-reversed) -> [256,512)
                const int col = (scan == 5) ? j : (256 + j);
                out[(size_t)t * (BATCH * 512) + (size_t)b * 512 + col] = hn;
            }
        }

        __syncthreads();  // all 4 waves' stores issued+drained before publishing
        if (tid == 0) {
            __hip_atomic_store(myflag, t + 1, __ATOMIC_RELEASE, __HIP_MEMORY_SCOPE_AGENT);
        }
    }
}

extern "C" void kernel_launch(void* const* d_in, const int* in_sizes, int n_in,
                              void* d_out, int out_size, void* d_ws, size_t ws_size,
                              hipStream_t stream) {
    (void)in_sizes; (void)n_in; (void)out_size; (void)ws_size;
    const float* x       = (const float*)d_in[0];
    const float* wihl0   = (const float*)d_in[1];
    const float* wihrest = (const float*)d_in[2];
    const float* whh     = (const float*)d_in[3];
    float* out = (float*)d_out;
    unsigned short* xhist = (unsigned short*)d_ws;
    unsigned short* hring = xhist + XHIST_TOTAL;
    int* flags = (int*)((char*)d_ws + FLAG_OFF_BYTES);

    // d_ws is poisoned 0xAA before every launch: flags MUST start at 0.
    hipMemsetAsync(flags, 0, 128, stream);

    // blockIdx = chunk*8 + scan; scans 0..6 (index 7 idle, keeps %8 XCD affinity)
    gru_pipeline<<<dim3(32), dim3(256), 0, stream>>>(x, wihl0, wihrest, whh, out,
                                                     xhist, hring, flags);
}